// Round 3
// baseline (720.694 us; speedup 1.0000x reference)
//
#include <hip/hip_runtime.h>
#include <hip/hip_bf16.h>

// ---------------------------------------------------------------------------
// Bahdanau attention, fused flash-style.  B=64, S=2048, E=D=U=512.
//  K1: pack W1 (fp32) -> bf16 in MFMA B-fragment order (ws)
//  K2: c[b,u] = H@W2 + b1 + b2   (fp32, ws)
//  K3: scores_ctx: per (b, 128-row strip), 8 waves x 16 rows:
//        afrag = 16 rows x K=512 bf16, PINNED IN AGPRs via inline-asm MFMA
//        "a" operand constraint (CDNA4 MFMA reads A from AGPR natively).
//        R1 post-mortem: with MFMA the allocator splits the unified file
//        ~half arch/half acc -> (512,2) = 256 total regs/wave = 2 waves/SIMD
//        = 8 waves/CU = 23% occ.  afrag (64 regs) -> AGPR half +
//        __launch_bounds__(512,4) targets 64 arch + 64 agpr = 128 total
//        -> 4 waves/SIMD, 2 blk/CU, 16 waves/CU.
//        R2 post-mortem: FAILED correctness (absmax 4e-2): inline-asm MFMA
//        gets NO compiler-inserted hazard nops.  Two raw hazards:
//        VALU-zero-init -> MFMA SrcC read, and MFMA dst -> VALU epilogue
//        read.  Fixed with explicit s_nop fences ("+v"(acc) ordering).
//        B 16KB tiles DMA double-buffered in LDS (global_load_lds).
//        score s = tanh(EO@W1 + c)·V ; strip m,l ; partial ctx from afrag
//  K4: combine 16 strips: M,L per b; context; weights = exp(s-M)/L.
// d_out layout: context [64*512] then weights [64*2048].
// ws: W1p 512K | cvec 128K | m 8K | l 8K | ck 4M   (~4.7 MB)
// ---------------------------------------------------------------------------

typedef __attribute__((ext_vector_type(8))) short bf16x8;   // 8 bf16 = 4 VGPR
typedef __attribute__((ext_vector_type(4))) float f32x4;

#define NB 64
#define NS 2048
#define NE 512
#define NU 512
#define NSTRIP 16   // strips per batch
#define SROWS 128   // rows per strip

// async 16B/lane global->LDS DMA: lds dest = wave-uniform base + lane*16
#define ASYNC_CP16(gsrc, ldst)                                               \
  __builtin_amdgcn_global_load_lds(                                          \
      (const __attribute__((address_space(1))) unsigned int*)(gsrc),         \
      (__attribute__((address_space(3))) unsigned int*)(ldst), 16, 0, 0)

__device__ __forceinline__ unsigned short f2bf(float f) {
  union { float f; unsigned int u; } x; x.f = f;
  unsigned int u = x.u;
  unsigned int r = (u + 0x7fffu + ((u >> 16) & 1u)) >> 16;  // RNE
  return (unsigned short)r;
}

__device__ __forceinline__ float bf2f(short s) {
  union { unsigned int u; float f; } x;
  x.u = ((unsigned int)(unsigned short)s) << 16;
  return x.f;
}

__device__ __forceinline__ float tanh_fast(float x) {
  x = fminf(fmaxf(x, -15.f), 15.f);
  float e = __expf(2.f * x);
  return 1.f - 2.f / (e + 1.f);
}

// --- K1: pack W1[k][n] (fp32 512x512) -> bf16 MFMA B-frag order:
//     W1p[(((nt*16+kt)*64 + lane)*8 + j)] = bf16(W1[kt*32+(lane>>4)*8+j][nt*16+(lane&15)])
__global__ __launch_bounds__(256) void pack_w1_kernel(
    const float* __restrict__ W1, unsigned short* __restrict__ W1p) {
  int t = blockIdx.x * 256 + threadIdx.x;
  int k = t >> 9, n = t & 511;
  int kt = k >> 5, kr = k & 31;
  int quad = kr >> 3, j = kr & 7;
  int l = (quad << 4) | (n & 15);
  int nt = n >> 4;
  int dst = ((((nt << 4) + kt) * 64 + l) << 3) + j;
  W1p[dst] = f2bf(W1[t]);
}

// --- K2: c[b][u] = sum_d H[b][d]*W2[d][u] + b1[u] + b2[u]
__global__ __launch_bounds__(512) void compute_c_kernel(
    const float* __restrict__ H, const float* __restrict__ W2,
    const float* __restrict__ b1, const float* __restrict__ b2,
    float* __restrict__ cvec) {
  const int b = blockIdx.x, u = threadIdx.x;
  __shared__ float hs[512];
  hs[u] = H[(b << 9) + u];
  __syncthreads();
  float s = 0.f;
#pragma unroll 8
  for (int d = 0; d < 512; d++) s = fmaf(hs[d], W2[(d << 9) + u], s);
  cvec[(b << 9) + u] = s + b1[u] + b2[u];
}

// --- K3: scores + softmax partials + context partials.
// grid 1024 (= 64 b * 16 strips of 128 rows), 512 thr (8 waves x 16 rows).
__global__ __launch_bounds__(512, 4) void scores_ctx_kernel(
    const float* __restrict__ EO, const unsigned short* __restrict__ W1p,
    const float* __restrict__ cvec, const float* __restrict__ V,
    float* __restrict__ scores, float* __restrict__ m_ws,
    float* __restrict__ l_ws, float* __restrict__ ck_ws) {
  __shared__ __align__(16) unsigned short Bs[2][8192];  // 2 x 16KB (1 nt tile)
  __shared__ float cs[512], vs[512];
  __shared__ float sc_l[SROWS], p_l[SROWS];
  __shared__ __align__(16) float cpart[8][512];

  const int tid = threadIdx.x;
  const int b = blockIdx.x >> 4;
  const int strip = blockIdx.x & 15;
  const int s0 = strip << 7;   // *128
  const int lane = tid & 63, wave = tid >> 6;
  const int quad = lane >> 4, col = lane & 15;

  const uint4* W1p4 = (const uint4*)W1p;  // one 16KB tile = 1024 uint4

  // ---- kick off DMA of B tile 0 (nt=0); 1024 uint4 = 2 x 512 lanes
#pragma unroll
  for (int i = 0; i < 2; i++)
    ASYNC_CP16(W1p4 + i * 512 + wave * 64 + lane,
               ((char*)&Bs[0][0]) + (i * 512 + wave * 64) * 16);

  cs[tid] = cvec[(b << 9) + tid];
  vs[tid] = V[tid];

  // ---- A-fragments straight from global: 16 rows x K=512, fp32 -> bf16.
  //      Lane (quad,col) holds row col, k = kt*32 + quad*8 + j.  64 regs,
  //      kept in the AGPR half (all loop uses are "a"-constrained).
  bf16x8 afrag[16];
  {
    const float* rp =
        EO + ((size_t)(b * NS + s0 + wave * 16 + col)) * NE + quad * 8;
#pragma unroll
    for (int kt = 0; kt < 16; kt++) {
      float4 x = *(const float4*)(rp + kt * 32);
      float4 y = *(const float4*)(rp + kt * 32 + 4);
      union { short s[8]; bf16x8 v; } u0;
      u0.s[0] = (short)f2bf(x.x); u0.s[1] = (short)f2bf(x.y);
      u0.s[2] = (short)f2bf(x.z); u0.s[3] = (short)f2bf(x.w);
      u0.s[4] = (short)f2bf(y.x); u0.s[5] = (short)f2bf(y.y);
      u0.s[6] = (short)f2bf(y.z); u0.s[7] = (short)f2bf(y.w);
      afrag[kt] = u0.v;
    }
  }

  __syncthreads();  // drains DMA vmcnt -> tile 0 ready

  float sacc[4] = {0.f, 0.f, 0.f, 0.f};

  for (int nt = 0; nt < 32; nt++) {
    const int cur = nt & 1;
    // DMA-prefetch next 16KB B tile into the other buffer (overlaps MFMAs)
    if (nt < 31) {
#pragma unroll
      for (int i = 0; i < 2; i++)
        ASYNC_CP16(W1p4 + (nt + 1) * 1024 + i * 512 + wave * 64 + lane,
                   ((char*)&Bs[cur ^ 1][0]) + (i * 512 + wave * 64) * 16);
    }
    f32x4 acc = {0.f, 0.f, 0.f, 0.f};
    // HW hazard fence: VALU write (zero-init) -> MFMA SrcC read needs wait
    // states; inline-asm MFMA gets no compiler-inserted nops (R2 failure).
    asm volatile("s_nop 1" : "+v"(acc));
    const bf16x8* bp = (const bf16x8*)&Bs[cur][0];
#pragma unroll
    for (int kt = 0; kt < 16; kt++) {
      bf16x8 bfr = bp[kt * 64 + lane];
      // A operand from AGPR ("a"), B from VGPR, C/D in VGPR.
      asm("v_mfma_f32_16x16x32_bf16 %0, %1, %2, %0"
          : "+v"(acc)
          : "a"(afrag[kt]), "v"(bfr));
    }
    // HW hazard fence: MFMA dst -> VALU read needs up to ~18 wait states.
    // "+v" (read-write) orders every later read of acc AFTER these nops.
    asm volatile("s_nop 7\n\ts_nop 7\n\ts_nop 7\n\ts_nop 3" : "+v"(acc));
    // fused epilogue: score partial += tanh(acc + c[u]) * V[u]
    int u = (nt << 4) + col;
    float cu = cs[u], vu = vs[u];
#pragma unroll
    for (int r = 0; r < 4; r++)
      sacc[r] += tanh_fast(acc[r] + cu) * vu;
    __syncthreads();  // all reads of cur done + next tile's DMA drained
  }

  // ---- reduce scores over the 16 col-lanes of each quad-group
#pragma unroll
  for (int m = 1; m < 16; m <<= 1)
#pragma unroll
    for (int r = 0; r < 4; r++)
      sacc[r] += __shfl_xor(sacc[r], m, 64);

  if (col == 0) {
#pragma unroll
    for (int r = 0; r < 4; r++) {
      int row = wave * 16 + quad * 4 + r;   // C/D: row = quad*4 + reg
      sc_l[row] = sacc[r];
      scores[(size_t)b * NS + s0 + row] = sacc[r];  // raw scores
    }
  }
  __syncthreads();

  // ---- strip max + l over the 128 rows (wave 0, 2 rows/lane)
  if (wave == 0) {
    float a0 = sc_l[lane], a1 = sc_l[lane + 64];
    float m0 = fmaxf(a0, a1);
#pragma unroll
    for (int off = 32; off; off >>= 1) m0 = fmaxf(m0, __shfl_xor(m0, off, 64));
    float e0 = __expf(a0 - m0), e1 = __expf(a1 - m0);
    p_l[lane] = e0; p_l[lane + 64] = e1;
    float p = e0 + e1;
#pragma unroll
    for (int off = 32; off; off >>= 1) p += __shfl_xor(p, off, 64);
    if (lane == 0) {
      m_ws[b * NSTRIP + strip] = m0;
      l_ws[b * NSTRIP + strip] = p;
    }
  }
  __syncthreads();

  // ---- context partials from register-resident bf16 EO fragments.
  // lane holds row (wave*16 + col), e = kt*32 + quad*8 + j.
  // (afrag reads here compile to v_accvgpr_read; read-after-read on the
  //  AGPRs, no hazard.)
  const float p0 = p_l[wave * 16 + col];
#pragma unroll
  for (int kt = 0; kt < 16; kt++) {
    float v[8];
#pragma unroll
    for (int j = 0; j < 8; j++) v[j] = p0 * bf2f(afrag[kt][j]);
#pragma unroll
    for (int m = 1; m < 16; m <<= 1)
#pragma unroll
      for (int j = 0; j < 8; j++) v[j] += __shfl_xor(v[j], m, 64);
    if (col == 0) {
      float* dst = &cpart[wave][kt * 32 + quad * 8];
      *(float4*)dst = make_float4(v[0], v[1], v[2], v[3]);
      *(float4*)(dst + 4) = make_float4(v[4], v[5], v[6], v[7]);
    }
  }
  __syncthreads();

  // ---- fold 8 wave-partials, write strip context partial to ws
  {
    float s = 0.f;
#pragma unroll
    for (int w = 0; w < 8; w++) s += cpart[w][tid];
    ck_ws[((size_t)(b * NSTRIP + strip)) * 512 + tid] = s;
  }
}

// --- K4: combine 16 strips: context + normalized weights.  64 blocks x 256.
__global__ __launch_bounds__(256) void combine_kernel(
    const float* __restrict__ m_ws, const float* __restrict__ l_ws,
    const float* __restrict__ ck_ws, float* __restrict__ ctx,
    float* __restrict__ w /* raw scores in, weights out */) {
  const int b = blockIdx.x, tid = threadIdx.x;
  __shared__ float msh[NSTRIP], lsh[NSTRIP];
  if (tid < NSTRIP) {
    msh[tid] = m_ws[b * NSTRIP + tid];
    lsh[tid] = l_ws[b * NSTRIP + tid];
  }
  __syncthreads();
  float M = msh[0];
#pragma unroll
  for (int k = 1; k < NSTRIP; k++) M = fmaxf(M, msh[k]);
  float L = 0.f;
#pragma unroll
  for (int k = 0; k < NSTRIP; k++) L += lsh[k] * __expf(msh[k] - M);
  const float invL = 1.f / L;

  float2 acc = {0.f, 0.f};
#pragma unroll
  for (int k = 0; k < NSTRIP; k++) {
    float sc = __expf(msh[k] - M);
    float2 t = *(const float2*)&ck_ws[((size_t)(b * NSTRIP + k)) * 512 + tid * 2];
    acc.x += sc * t.x; acc.y += sc * t.y;
  }
  acc.x *= invL; acc.y *= invL;
  *(float2*)&ctx[(b << 9) + tid * 2] = acc;

  float* row = w + (size_t)b * NS;
#pragma unroll
  for (int i = 0; i < 8; i++) {
    float s = row[i * 256 + tid];
    row[i * 256 + tid] = __expf(s - M) * invL;
  }
}

extern "C" void kernel_launch(void* const* d_in, const int* in_sizes, int n_in,
                              void* d_out, int out_size, void* d_ws, size_t ws_size,
                              hipStream_t stream) {
  (void)in_sizes; (void)n_in; (void)out_size; (void)ws_size;
  const float* H  = (const float*)d_in[0];
  const float* EO = (const float*)d_in[1];
  const float* W1 = (const float*)d_in[2];
  const float* b1 = (const float*)d_in[3];
  const float* W2 = (const float*)d_in[4];
  const float* b2 = (const float*)d_in[5];
  const float* V  = (const float*)d_in[6];
  // d_in[7] = bv: softmax is shift-invariant -> unused.

  float* out_ctx = (float*)d_out;            // [64*512]
  float* out_w   = (float*)d_out + NB * NE;  // [64*2048] raw scores -> weights

  char* ws = (char*)d_ws;
  unsigned short* W1p = (unsigned short*)ws;            // 512 KB
  float* cvec = (float*)(ws + 512 * 1024);              // 128 KB
  float* m_ws = (float*)(ws + 640 * 1024);              // 8 KB
  float* l_ws = (float*)(ws + 656 * 1024);              // 8 KB
  float* ck_ws = (float*)(ws + 672 * 1024);             // 4 MB

  pack_w1_kernel<<<1024, 256, 0, stream>>>(W1, W1p);
  compute_c_kernel<<<NB, 512, 0, stream>>>(H, W2, b1, b2, cvec);
  scores_ctx_kernel<<<NB * NSTRIP, 512, 0, stream>>>(EO, W1p, cvec, V, out_w,
                                                     m_ws, l_ws, ck_ws);
  combine_kernel<<<NB, 256, 0, stream>>>(m_ws, l_ws, ck_ws, out_ctx, out_w);
}

// Round 4
// 717.320 us; speedup vs baseline: 1.0047x; 1.0047x over previous
//
#include <hip/hip_runtime.h>
#include <hip/hip_bf16.h>

// ---------------------------------------------------------------------------
// Bahdanau attention, fused flash-style.  B=64, S=2048, E=D=U=512.
//  K1: pack W1 (fp32) -> bf16 in MFMA B-fragment order (ws)
//  K2: c[b,u] = H@W2 + b1 + b2   (fp32, ws)
//  K3: scores_ctx: per (b, 128-row strip), 8 waves x 16 rows:
//        afrag = 16 rows x K=512 bf16, PINNED IN AGPRs via inline-asm MFMA
//        "a" operand constraint.  (512,4): 64 arch + 64 agpr = 128 total
//        -> 4 waves/SIMD, 2 blk/CU, 16 waves/CU (R3: 45% occ, confirmed).
//        R2 post-mortem: inline-asm MFMA gets NO compiler hazard nops ->
//        explicit s_nop fences (VALU->MFMA SrcC, MFMA->VALU dst read).
//        R3 post-mortem: 64-arch cap spilled (~600 MB scratch writes) --
//        scheduler hoisted all 16 B-frag LDS loads (64 VGPR) and
//        interleaved all 16 ctx-tail shuffle chains (~128 VGPR).  Fix:
//        sched_barrier(0) pressure fences -- B loads in groups of 4
//        (<=16 VGPR in flight), prologue afrag build in groups of 4,
//        ctx tail per-kt.  Steady-state arch live set ~40-55 <= 64.
//        B 16KB tiles DMA double-buffered in LDS (global_load_lds).
//        score s = tanh(EO@W1 + c)·V ; strip m,l ; partial ctx from afrag
//  K4: combine 16 strips: M,L per b; context; weights = exp(s-M)/L.
// d_out layout: context [64*512] then weights [64*2048].
// ws: W1p 512K | cvec 128K | m 8K | l 8K | ck 4M   (~4.7 MB)
// ---------------------------------------------------------------------------

typedef __attribute__((ext_vector_type(8))) short bf16x8;   // 8 bf16 = 4 VGPR
typedef __attribute__((ext_vector_type(4))) float f32x4;

#define NB 64
#define NS 2048
#define NE 512
#define NU 512
#define NSTRIP 16   // strips per batch
#define SROWS 128   // rows per strip

// async 16B/lane global->LDS DMA: lds dest = wave-uniform base + lane*16
#define ASYNC_CP16(gsrc, ldst)                                               \
  __builtin_amdgcn_global_load_lds(                                          \
      (const __attribute__((address_space(1))) unsigned int*)(gsrc),         \
      (__attribute__((address_space(3))) unsigned int*)(ldst), 16, 0, 0)

#define SCHED_FENCE() __builtin_amdgcn_sched_barrier(0)

__device__ __forceinline__ unsigned short f2bf(float f) {
  union { float f; unsigned int u; } x; x.f = f;
  unsigned int u = x.u;
  unsigned int r = (u + 0x7fffu + ((u >> 16) & 1u)) >> 16;  // RNE
  return (unsigned short)r;
}

__device__ __forceinline__ float bf2f(short s) {
  union { unsigned int u; float f; } x;
  x.u = ((unsigned int)(unsigned short)s) << 16;
  return x.f;
}

__device__ __forceinline__ float tanh_fast(float x) {
  x = fminf(fmaxf(x, -15.f), 15.f);
  float e = __expf(2.f * x);
  return 1.f - 2.f / (e + 1.f);
}

// --- K1: pack W1[k][n] (fp32 512x512) -> bf16 MFMA B-frag order:
//     W1p[(((nt*16+kt)*64 + lane)*8 + j)] = bf16(W1[kt*32+(lane>>4)*8+j][nt*16+(lane&15)])
__global__ __launch_bounds__(256) void pack_w1_kernel(
    const float* __restrict__ W1, unsigned short* __restrict__ W1p) {
  int t = blockIdx.x * 256 + threadIdx.x;
  int k = t >> 9, n = t & 511;
  int kt = k >> 5, kr = k & 31;
  int quad = kr >> 3, j = kr & 7;
  int l = (quad << 4) | (n & 15);
  int nt = n >> 4;
  int dst = ((((nt << 4) + kt) * 64 + l) << 3) + j;
  W1p[dst] = f2bf(W1[t]);
}

// --- K2: c[b][u] = sum_d H[b][d]*W2[d][u] + b1[u] + b2[u]
__global__ __launch_bounds__(512) void compute_c_kernel(
    const float* __restrict__ H, const float* __restrict__ W2,
    const float* __restrict__ b1, const float* __restrict__ b2,
    float* __restrict__ cvec) {
  const int b = blockIdx.x, u = threadIdx.x;
  __shared__ float hs[512];
  hs[u] = H[(b << 9) + u];
  __syncthreads();
  float s = 0.f;
#pragma unroll 8
  for (int d = 0; d < 512; d++) s = fmaf(hs[d], W2[(d << 9) + u], s);
  cvec[(b << 9) + u] = s + b1[u] + b2[u];
}

// --- K3: scores + softmax partials + context partials.
// grid 1024 (= 64 b * 16 strips of 128 rows), 512 thr (8 waves x 16 rows).
__global__ __launch_bounds__(512, 4) void scores_ctx_kernel(
    const float* __restrict__ EO, const unsigned short* __restrict__ W1p,
    const float* __restrict__ cvec, const float* __restrict__ V,
    float* __restrict__ scores, float* __restrict__ m_ws,
    float* __restrict__ l_ws, float* __restrict__ ck_ws) {
  __shared__ __align__(16) unsigned short Bs[2][8192];  // 2 x 16KB (1 nt tile)
  __shared__ float cs[512], vs[512];
  __shared__ float sc_l[SROWS], p_l[SROWS];
  __shared__ __align__(16) float cpart[8][512];

  const int tid = threadIdx.x;
  const int b = blockIdx.x >> 4;
  const int strip = blockIdx.x & 15;
  const int s0 = strip << 7;   // *128
  const int lane = tid & 63, wave = tid >> 6;
  const int quad = lane >> 4, col = lane & 15;

  const uint4* W1p4 = (const uint4*)W1p;  // one 16KB tile = 1024 uint4

  // ---- kick off DMA of B tile 0 (nt=0); 1024 uint4 = 2 x 512 lanes
#pragma unroll
  for (int i = 0; i < 2; i++)
    ASYNC_CP16(W1p4 + i * 512 + wave * 64 + lane,
               ((char*)&Bs[0][0]) + (i * 512 + wave * 64) * 16);

  cs[tid] = cvec[(b << 9) + tid];
  vs[tid] = V[tid];

  // ---- A-fragments straight from global: 16 rows x K=512, fp32 -> bf16.
  //      Lane (quad,col) holds row col, k = kt*32 + quad*8 + j.  64 regs,
  //      kept in the AGPR half (all loop uses are "a"-constrained).
  //      Groups of 4 kt + sched fence: caps transient arch pressure ~40.
  bf16x8 afrag[16];
  {
    const float* rp =
        EO + ((size_t)(b * NS + s0 + wave * 16 + col)) * NE + quad * 8;
#pragma unroll
    for (int g = 0; g < 4; g++) {
#pragma unroll
      for (int k2 = 0; k2 < 4; k2++) {
        int kt = g * 4 + k2;
        float4 x = *(const float4*)(rp + kt * 32);
        float4 y = *(const float4*)(rp + kt * 32 + 4);
        union { short s[8]; bf16x8 v; } u0;
        u0.s[0] = (short)f2bf(x.x); u0.s[1] = (short)f2bf(x.y);
        u0.s[2] = (short)f2bf(x.z); u0.s[3] = (short)f2bf(x.w);
        u0.s[4] = (short)f2bf(y.x); u0.s[5] = (short)f2bf(y.y);
        u0.s[6] = (short)f2bf(y.z); u0.s[7] = (short)f2bf(y.w);
        afrag[kt] = u0.v;
      }
      SCHED_FENCE();
    }
  }

  __syncthreads();  // drains DMA vmcnt -> tile 0 ready

  float sacc[4] = {0.f, 0.f, 0.f, 0.f};

  for (int nt = 0; nt < 32; nt++) {
    const int cur = nt & 1;
    // DMA-prefetch next 16KB B tile into the other buffer (overlaps MFMAs)
    if (nt < 31) {
#pragma unroll
      for (int i = 0; i < 2; i++)
        ASYNC_CP16(W1p4 + (nt + 1) * 1024 + i * 512 + wave * 64 + lane,
                   ((char*)&Bs[cur ^ 1][0]) + (i * 512 + wave * 64) * 16);
    }
    f32x4 acc = {0.f, 0.f, 0.f, 0.f};
    // HW hazard fence: VALU write (zero-init) -> MFMA SrcC read wait states.
    asm volatile("s_nop 1" : "+v"(acc));
    const bf16x8* bp = (const bf16x8*)&Bs[cur][0];
    // B-frag loads in groups of 4 (<=16 VGPR in flight); fence stops the
    // scheduler from hoisting later groups' loads (R3 spill cause).
#pragma unroll
    for (int g = 0; g < 4; g++) {
      bf16x8 q0 = bp[(g * 4 + 0) * 64 + lane];
      bf16x8 q1 = bp[(g * 4 + 1) * 64 + lane];
      bf16x8 q2 = bp[(g * 4 + 2) * 64 + lane];
      bf16x8 q3 = bp[(g * 4 + 3) * 64 + lane];
      asm("v_mfma_f32_16x16x32_bf16 %0, %1, %2, %0"
          : "+v"(acc) : "a"(afrag[g * 4 + 0]), "v"(q0));
      asm("v_mfma_f32_16x16x32_bf16 %0, %1, %2, %0"
          : "+v"(acc) : "a"(afrag[g * 4 + 1]), "v"(q1));
      asm("v_mfma_f32_16x16x32_bf16 %0, %1, %2, %0"
          : "+v"(acc) : "a"(afrag[g * 4 + 2]), "v"(q2));
      asm("v_mfma_f32_16x16x32_bf16 %0, %1, %2, %0"
          : "+v"(acc) : "a"(afrag[g * 4 + 3]), "v"(q3));
      SCHED_FENCE();
    }
    // HW hazard fence: MFMA dst -> VALU read needs up to ~18 wait states.
    asm volatile("s_nop 7\n\ts_nop 7\n\ts_nop 7\n\ts_nop 3" : "+v"(acc));
    // fused epilogue: score partial += tanh(acc + c[u]) * V[u]
    int u = (nt << 4) + col;
    float cu = cs[u], vu = vs[u];
#pragma unroll
    for (int r = 0; r < 4; r++)
      sacc[r] += tanh_fast(acc[r] + cu) * vu;
    __syncthreads();  // all reads of cur done + next tile's DMA drained
  }

  // ---- reduce scores over the 16 col-lanes of each quad-group
#pragma unroll
  for (int m = 1; m < 16; m <<= 1)
#pragma unroll
    for (int r = 0; r < 4; r++)
      sacc[r] += __shfl_xor(sacc[r], m, 64);

  if (col == 0) {
#pragma unroll
    for (int r = 0; r < 4; r++) {
      int row = wave * 16 + quad * 4 + r;   // C/D: row = quad*4 + reg
      sc_l[row] = sacc[r];
      scores[(size_t)b * NS + s0 + row] = sacc[r];  // raw scores
    }
  }
  __syncthreads();

  // ---- strip max + l over the 128 rows (wave 0, 2 rows/lane)
  if (wave == 0) {
    float a0 = sc_l[lane], a1 = sc_l[lane + 64];
    float m0 = fmaxf(a0, a1);
#pragma unroll
    for (int off = 32; off; off >>= 1) m0 = fmaxf(m0, __shfl_xor(m0, off, 64));
    float e0 = __expf(a0 - m0), e1 = __expf(a1 - m0);
    p_l[lane] = e0; p_l[lane + 64] = e1;
    float p = e0 + e1;
#pragma unroll
    for (int off = 32; off; off >>= 1) p += __shfl_xor(p, off, 64);
    if (lane == 0) {
      m_ws[b * NSTRIP + strip] = m0;
      l_ws[b * NSTRIP + strip] = p;
    }
  }
  __syncthreads();

  // ---- context partials from register-resident bf16 EO fragments.
  // lane holds row (wave*16 + col), e = kt*32 + quad*8 + j.
  // Per-kt fence: stops the scheduler interleaving 16 shuffle chains
  // (~128 VGPR transient -> R3 spill cause #2).
  const float p0 = p_l[wave * 16 + col];
#pragma unroll
  for (int kt = 0; kt < 16; kt++) {
    float v[8];
#pragma unroll
    for (int j = 0; j < 8; j++) v[j] = p0 * bf2f(afrag[kt][j]);
#pragma unroll
    for (int m = 1; m < 16; m <<= 1)
#pragma unroll
      for (int j = 0; j < 8; j++) v[j] += __shfl_xor(v[j], m, 64);
    if (col == 0) {
      float* dst = &cpart[wave][kt * 32 + quad * 8];
      *(float4*)dst = make_float4(v[0], v[1], v[2], v[3]);
      *(float4*)(dst + 4) = make_float4(v[4], v[5], v[6], v[7]);
    }
    SCHED_FENCE();
  }
  __syncthreads();

  // ---- fold 8 wave-partials, write strip context partial to ws
  {
    float s = 0.f;
#pragma unroll
    for (int w = 0; w < 8; w++) s += cpart[w][tid];
    ck_ws[((size_t)(b * NSTRIP + strip)) * 512 + tid] = s;
  }
}

// --- K4: combine 16 strips: context + normalized weights.  64 blocks x 256.
__global__ __launch_bounds__(256) void combine_kernel(
    const float* __restrict__ m_ws, const float* __restrict__ l_ws,
    const float* __restrict__ ck_ws, float* __restrict__ ctx,
    float* __restrict__ w /* raw scores in, weights out */) {
  const int b = blockIdx.x, tid = threadIdx.x;
  __shared__ float msh[NSTRIP], lsh[NSTRIP];
  if (tid < NSTRIP) {
    msh[tid] = m_ws[b * NSTRIP + tid];
    lsh[tid] = l_ws[b * NSTRIP + tid];
  }
  __syncthreads();
  float M = msh[0];
#pragma unroll
  for (int k = 1; k < NSTRIP; k++) M = fmaxf(M, msh[k]);
  float L = 0.f;
#pragma unroll
  for (int k = 0; k < NSTRIP; k++) L += lsh[k] * __expf(msh[k] - M);
  const float invL = 1.f / L;

  float2 acc = {0.f, 0.f};
#pragma unroll
  for (int k = 0; k < NSTRIP; k++) {
    float sc = __expf(msh[k] - M);
    float2 t = *(const float2*)&ck_ws[((size_t)(b * NSTRIP + k)) * 512 + tid * 2];
    acc.x += sc * t.x; acc.y += sc * t.y;
  }
  acc.x *= invL; acc.y *= invL;
  *(float2*)&ctx[(b << 9) + tid * 2] = acc;

  float* row = w + (size_t)b * NS;
#pragma unroll
  for (int i = 0; i < 8; i++) {
    float s = row[i * 256 + tid];
    row[i * 256 + tid] = __expf(s - M) * invL;
  }
}

extern "C" void kernel_launch(void* const* d_in, const int* in_sizes, int n_in,
                              void* d_out, int out_size, void* d_ws, size_t ws_size,
                              hipStream_t stream) {
  (void)in_sizes; (void)n_in; (void)out_size; (void)ws_size;
  const float* H  = (const float*)d_in[0];
  const float* EO = (const float*)d_in[1];
  const float* W1 = (const float*)d_in[2];
  const float* b1 = (const float*)d_in[3];
  const float* W2 = (const float*)d_in[4];
  const float* b2 = (const float*)d_in[5];
  const float* V  = (const float*)d_in[6];
  // d_in[7] = bv: softmax is shift-invariant -> unused.

  float* out_ctx = (float*)d_out;            // [64*512]
  float* out_w   = (float*)d_out + NB * NE;  // [64*2048] raw scores -> weights

  char* ws = (char*)d_ws;
  unsigned short* W1p = (unsigned short*)ws;            // 512 KB
  float* cvec = (float*)(ws + 512 * 1024);              // 128 KB
  float* m_ws = (float*)(ws + 640 * 1024);              // 8 KB
  float* l_ws = (float*)(ws + 656 * 1024);              // 8 KB
  float* ck_ws = (float*)(ws + 672 * 1024);             // 4 MB

  pack_w1_kernel<<<1024, 256, 0, stream>>>(W1, W1p);
  compute_c_kernel<<<NB, 512, 0, stream>>>(H, W2, b1, b2, cvec);
  scores_ctx_kernel<<<NB * NSTRIP, 512, 0, stream>>>(EO, W1p, cvec, V, out_w,
                                                     m_ws, l_ws, ck_ws);
  combine_kernel<<<NB, 256, 0, stream>>>(m_ws, l_ws, ck_ws, out_ctx, out_w);
}

// Round 6
// 687.033 us; speedup vs baseline: 1.0490x; 1.0441x over previous
//
#include <hip/hip_runtime.h>
#include <hip/hip_bf16.h>

// ---------------------------------------------------------------------------
// Bahdanau attention, fused flash-style.  B=64, S=2048, E=D=U=512.
//  K1: pack W1 (fp32) -> bf16 in MFMA B-fragment order (ws)
//  K2: c[b,u] = H@W2 + b1 + b2   (fp32, ws)
//  K3: scores_ctx: per (b, 64-row strip), 4 waves x 16 rows:
//        afrag = 16 rows x K=512 bf16 in 64 VGPRs (register-resident EO).
//        R3/R4 post-mortem: forcing afrag->AGPR to hit 128 total regs
//        spilled ~600 MB scratch in both attempts (and prior session's
//        (256,3) spilled too) -> 64-arch is infeasible; route abandoned.
//        R5: occupancy stays 23%; instead DELETE the per-nt serialization:
//        W1p is 512 KB, shared by all blocks -> L2/L3-resident; all waves
//        in a CU read the same 16 KB tile -> L1 broadcast.  So B-frags are
//        loaded DIRECTLY from global via L1 (coalesced 1 KB/instr):
//        no LDS staging, no DMA, no double buffer, and NO per-nt
//        __syncthreads (prev: 32 barriers x vmcnt(0) drain ~5000 cy/iter).
//        score s = tanh(EO@W1 + c)·V ; strip m,l ; partial ctx from afrag
//  K4: combine 32 strips: M,L per b; context; weights = exp(s-M)/L.
// d_out layout: context [64*512] then weights [64*2048].
// ws: W1p 512K | cvec 128K | m 8K | l 8K | ck 4M   (~4.7 MB)
// (R5 bench was an infra failure -- container died before compile; this is
//  an identical resubmission.)
// ---------------------------------------------------------------------------

typedef __attribute__((ext_vector_type(8))) short bf16x8;   // 8 bf16 = 4 VGPR
typedef __attribute__((ext_vector_type(4))) float f32x4;

#define NB 64
#define NS 2048
#define NE 512
#define NU 512

__device__ __forceinline__ unsigned short f2bf(float f) {
  union { float f; unsigned int u; } x; x.f = f;
  unsigned int u = x.u;
  unsigned int r = (u + 0x7fffu + ((u >> 16) & 1u)) >> 16;  // RNE
  return (unsigned short)r;
}

__device__ __forceinline__ float bf2f(short s) {
  union { unsigned int u; float f; } x;
  x.u = ((unsigned int)(unsigned short)s) << 16;
  return x.f;
}

__device__ __forceinline__ float tanh_fast(float x) {
  x = fminf(fmaxf(x, -15.f), 15.f);
  float e = __expf(2.f * x);
  return 1.f - 2.f / (e + 1.f);
}

// --- K1: pack W1[k][n] (fp32 512x512) -> bf16 MFMA B-frag order:
//     W1p[(((nt*16+kt)*64 + lane)*8 + j)] = bf16(W1[kt*32+(lane>>4)*8+j][nt*16+(lane&15)])
__global__ __launch_bounds__(256) void pack_w1_kernel(
    const float* __restrict__ W1, unsigned short* __restrict__ W1p) {
  int t = blockIdx.x * 256 + threadIdx.x;
  int k = t >> 9, n = t & 511;
  int kt = k >> 5, kr = k & 31;
  int quad = kr >> 3, j = kr & 7;
  int l = (quad << 4) | (n & 15);
  int nt = n >> 4;
  int dst = ((((nt << 4) + kt) * 64 + l) << 3) + j;
  W1p[dst] = f2bf(W1[t]);
}

// --- K2: c[b][u] = sum_d H[b][d]*W2[d][u] + b1[u] + b2[u]
__global__ __launch_bounds__(512) void compute_c_kernel(
    const float* __restrict__ H, const float* __restrict__ W2,
    const float* __restrict__ b1, const float* __restrict__ b2,
    float* __restrict__ cvec) {
  const int b = blockIdx.x, u = threadIdx.x;
  __shared__ float hs[512];
  hs[u] = H[(b << 9) + u];
  __syncthreads();
  float s = 0.f;
#pragma unroll 8
  for (int d = 0; d < 512; d++) s = fmaf(hs[d], W2[(d << 9) + u], s);
  cvec[(b << 9) + u] = s + b1[u] + b2[u];
}

// --- K3: scores + softmax partials + context partials.
// grid 2048 (= 64 b * 32 strips of 64 rows), 256 thr (4 waves x 16 rows).
// No LDS B-staging: B-frags stream from W1p via L1/L2 (see header).
__global__ __launch_bounds__(256, 2) void scores_ctx_kernel(
    const float* __restrict__ EO, const unsigned short* __restrict__ W1p,
    const float* __restrict__ cvec, const float* __restrict__ V,
    float* __restrict__ scores, float* __restrict__ m_ws,
    float* __restrict__ l_ws, float* __restrict__ ck_ws) {
  __shared__ float cs[512], vs[512];
  __shared__ float sc_l[64], p_l[64];
  __shared__ __align__(16) float cpart[4][512];
  __shared__ float m_sh;

  const int tid = threadIdx.x;
  const int b = blockIdx.x >> 5;
  const int strip = blockIdx.x & 31;
  const int s0 = strip << 6;   // *64
  const int lane = tid & 63, wave = tid >> 6;
  const int quad = lane >> 4, col = lane & 15;

  cs[tid] = cvec[(b << 9) + tid];
  cs[tid + 256] = cvec[(b << 9) + 256 + tid];
  vs[tid] = V[tid];
  vs[tid + 256] = V[256 + tid];

  // ---- A-fragments straight from global: 16 rows x K=512, fp32 -> bf16.
  //      Lane (quad,col) holds row col, k = kt*32 + quad*8 + j.  64 VGPRs.
  bf16x8 afrag[16];
  {
    const float* rp =
        EO + ((size_t)(b * NS + s0 + wave * 16 + col)) * NE + quad * 8;
#pragma unroll
    for (int kt = 0; kt < 16; kt++) {
      float4 x = *(const float4*)(rp + kt * 32);
      float4 y = *(const float4*)(rp + kt * 32 + 4);
      union { short s[8]; bf16x8 v; } u0;
      u0.s[0] = (short)f2bf(x.x); u0.s[1] = (short)f2bf(x.y);
      u0.s[2] = (short)f2bf(x.z); u0.s[3] = (short)f2bf(x.w);
      u0.s[4] = (short)f2bf(y.x); u0.s[5] = (short)f2bf(y.y);
      u0.s[6] = (short)f2bf(y.z); u0.s[7] = (short)f2bf(y.w);
      afrag[kt] = u0.v;
    }
  }

  __syncthreads();  // cs/vs visible to all waves (only barrier before tail)

  float sacc[4] = {0.f, 0.f, 0.f, 0.f};
  const bf16x8* bp_all = (const bf16x8*)W1p;  // 1024 frags per 16KB nt tile

  for (int nt = 0; nt < 32; nt++) {
    const bf16x8* bp = bp_all + nt * 1024;
    f32x4 acc = {0.f, 0.f, 0.f, 0.f};
#pragma unroll
    for (int kt = 0; kt < 16; kt++) {
      bf16x8 bfr = bp[kt * 64 + lane];  // global ld, L1-broadcast across waves
      acc = __builtin_amdgcn_mfma_f32_16x16x32_bf16(afrag[kt], bfr, acc, 0, 0, 0);
    }
    // fused epilogue: score partial += tanh(acc + c[u]) * V[u]
    int u = (nt << 4) + col;
    float cu = cs[u], vu = vs[u];
#pragma unroll
    for (int r = 0; r < 4; r++)
      sacc[r] += tanh_fast(acc[r] + cu) * vu;
    // no barrier: no shared state touched in the loop
  }

  // ---- reduce scores over the 16 col-lanes of each quad-group
#pragma unroll
  for (int m = 1; m < 16; m <<= 1)
#pragma unroll
    for (int r = 0; r < 4; r++)
      sacc[r] += __shfl_xor(sacc[r], m, 64);

  if (col == 0) {
#pragma unroll
    for (int r = 0; r < 4; r++) {
      int row = wave * 16 + quad * 4 + r;   // C/D: row = quad*4 + reg
      sc_l[row] = sacc[r];
      scores[(size_t)b * NS + s0 + row] = sacc[r];  // raw scores
    }
  }
  __syncthreads();

  // ---- strip max + l over the 64 rows (wave 0)
  if (wave == 0) {
    float m0 = sc_l[lane];
#pragma unroll
    for (int off = 32; off; off >>= 1) m0 = fmaxf(m0, __shfl_xor(m0, off, 64));
    if (lane == 0) m_sh = m0;
    float p = __expf(sc_l[lane] - m0);
    p_l[lane] = p;
#pragma unroll
    for (int off = 32; off; off >>= 1) p += __shfl_xor(p, off, 64);
    if (lane == 0) {
      m_ws[b * 32 + strip] = m0;
      l_ws[b * 32 + strip] = p;
    }
  }
  __syncthreads();

  // ---- context partials from register-resident bf16 EO fragments.
  // lane holds row (wave*16 + col), e = kt*32 + quad*8 + j.
  const float p0 = p_l[wave * 16 + col];
#pragma unroll
  for (int kt = 0; kt < 16; kt++) {
    float v[8];
#pragma unroll
    for (int j = 0; j < 8; j++) v[j] = p0 * bf2f(afrag[kt][j]);
#pragma unroll
    for (int m = 1; m < 16; m <<= 1)
#pragma unroll
      for (int j = 0; j < 8; j++) v[j] += __shfl_xor(v[j], m, 64);
    if (col == 0) {
      float* dst = &cpart[wave][kt * 32 + quad * 8];
      *(float4*)dst = make_float4(v[0], v[1], v[2], v[3]);
      *(float4*)(dst + 4) = make_float4(v[4], v[5], v[6], v[7]);
    }
  }
  __syncthreads();

  // ---- fold 4 wave-partials, write strip context partial to ws
  {
    float2 s = {0.f, 0.f};
#pragma unroll
    for (int w = 0; w < 4; w++) {
      float2 t = *(const float2*)&cpart[w][tid * 2];
      s.x += t.x; s.y += t.y;
    }
    *(float2*)&ck_ws[((size_t)(b * 32 + strip)) * 512 + tid * 2] = s;
  }
}

// --- K4: combine 32 strips: context + normalized weights.  64 blocks x 256.
__global__ __launch_bounds__(256) void combine_kernel(
    const float* __restrict__ m_ws, const float* __restrict__ l_ws,
    const float* __restrict__ ck_ws, float* __restrict__ ctx,
    float* __restrict__ w /* raw scores in, weights out */) {
  const int b = blockIdx.x, tid = threadIdx.x;
  __shared__ float msh[32], lsh[32];
  if (tid < 32) {
    msh[tid] = m_ws[b * 32 + tid];
    lsh[tid] = l_ws[b * 32 + tid];
  }
  __syncthreads();
  float M = msh[0];
#pragma unroll
  for (int k = 1; k < 32; k++) M = fmaxf(M, msh[k]);
  float L = 0.f;
#pragma unroll
  for (int k = 0; k < 32; k++) L += lsh[k] * __expf(msh[k] - M);
  const float invL = 1.f / L;

  float2 acc = {0.f, 0.f};
#pragma unroll
  for (int k = 0; k < 32; k++) {
    float sc = __expf(msh[k] - M);
    float2 t = *(const float2*)&ck_ws[((size_t)(b * 32 + k)) * 512 + tid * 2];
    acc.x += sc * t.x; acc.y += sc * t.y;
  }
  acc.x *= invL; acc.y *= invL;
  *(float2*)&ctx[(b << 9) + tid * 2] = acc;

  float* row = w + (size_t)b * NS;
#pragma unroll
  for (int i = 0; i < 8; i++) {
    float s = row[i * 256 + tid];
    row[i * 256 + tid] = __expf(s - M) * invL;
  }
}

extern "C" void kernel_launch(void* const* d_in, const int* in_sizes, int n_in,
                              void* d_out, int out_size, void* d_ws, size_t ws_size,
                              hipStream_t stream) {
  (void)in_sizes; (void)n_in; (void)out_size; (void)ws_size;
  const float* H  = (const float*)d_in[0];
  const float* EO = (const float*)d_in[1];
  const float* W1 = (const float*)d_in[2];
  const float* b1 = (const float*)d_in[3];
  const float* W2 = (const float*)d_in[4];
  const float* b2 = (const float*)d_in[5];
  const float* V  = (const float*)d_in[6];
  // d_in[7] = bv: softmax is shift-invariant -> unused.

  float* out_ctx = (float*)d_out;            // [64*512]
  float* out_w   = (float*)d_out + NB * NE;  // [64*2048] raw scores -> weights

  char* ws = (char*)d_ws;
  unsigned short* W1p = (unsigned short*)ws;            // 512 KB
  float* cvec = (float*)(ws + 512 * 1024);              // 128 KB
  float* m_ws = (float*)(ws + 640 * 1024);              // 8 KB
  float* l_ws = (float*)(ws + 656 * 1024);              // 8 KB
  float* ck_ws = (float*)(ws + 672 * 1024);             // 4 MB

  pack_w1_kernel<<<1024, 256, 0, stream>>>(W1, W1p);
  compute_c_kernel<<<NB, 512, 0, stream>>>(H, W2, b1, b2, cvec);
  scores_ctx_kernel<<<2048, 256, 0, stream>>>(EO, W1p, cvec, V, out_w,
                                              m_ws, l_ws, ck_ws);
  combine_kernel<<<NB, 256, 0, stream>>>(m_ws, l_ws, ck_ws, out_ctx, out_w);
}

// Round 7
// 536.732 us; speedup vs baseline: 1.3427x; 1.2800x over previous
//
#include <hip/hip_runtime.h>
#include <hip/hip_bf16.h>

// ---------------------------------------------------------------------------
// Bahdanau attention, fused flash-style.  B=64, S=2048, E=D=U=512.
//  K1: pack W1 (fp32) -> bf16 in MFMA B-fragment order (ws)
//  K2: c[b,u] = H@W2 + b1 + b2   (fp32, ws)
//  K3: scores_ctx: per (b, 64-row strip), 4 waves x 16 rows:
//        afrag = 16 rows x K=512 bf16 in 64 VGPRs (register-resident EO).
//        History: (512,4)+AGPR spilled 600MB (R3/R4); no-LDS L1-stream
//        regressed 258->384 (R6: ~200cy L1 latency on every MFMA operand,
//        8 waves can't hide it).  R0's defect: per-nt __syncthreads drains
//        vmcnt(0) -> waits for the JUST-ISSUED prefetch DMA every iter.
//        R7: counted-vmcnt pipeline (guide T4): 3 LDS buffers, 2 tiles
//        prefetched ahead; per iter  wait vmcnt(8) [oldest tile only] ->
//        s_barrier -> MFMA from buf[t%3] -> s_barrier -> DMA tile t+3.
//        Every wave does the same wait before the barrier, so tile t is
//        globally ready WITHOUT draining tiles t+1,t+2 in flight.
//        score s = tanh(EO@W1 + c)·V ; strip m,l ; partial ctx from afrag
//  K4: combine 32 strips: M,L per b; context; weights = exp(s-M)/L.
// d_out layout: context [64*512] then weights [64*2048].
// ws: W1p 512K | cvec 128K | m 8K | l 8K | ck 4M   (~4.7 MB)
// ---------------------------------------------------------------------------

typedef __attribute__((ext_vector_type(8))) short bf16x8;   // 8 bf16 = 4 VGPR
typedef __attribute__((ext_vector_type(4))) float f32x4;

#define NB 64
#define NS 2048
#define NE 512
#define NU 512

// async 16B/lane global->LDS DMA: lds dest = wave-uniform base + lane*16
#define ASYNC_CP16(gsrc, ldst)                                               \
  __builtin_amdgcn_global_load_lds(                                          \
      (const __attribute__((address_space(1))) unsigned int*)(gsrc),         \
      (__attribute__((address_space(3))) unsigned int*)(ldst), 16, 0, 0)

// counted VMEM wait: only the oldest (outstanding-N) loads must retire.
#define WAITVM(N) asm volatile("s_waitcnt vmcnt(" #N ")" ::: "memory")

__device__ __forceinline__ unsigned short f2bf(float f) {
  union { float f; unsigned int u; } x; x.f = f;
  unsigned int u = x.u;
  unsigned int r = (u + 0x7fffu + ((u >> 16) & 1u)) >> 16;  // RNE
  return (unsigned short)r;
}

__device__ __forceinline__ float bf2f(short s) {
  union { unsigned int u; float f; } x;
  x.u = ((unsigned int)(unsigned short)s) << 16;
  return x.f;
}

__device__ __forceinline__ float tanh_fast(float x) {
  x = fminf(fmaxf(x, -15.f), 15.f);
  float e = __expf(2.f * x);
  return 1.f - 2.f / (e + 1.f);
}

// --- K1: pack W1[k][n] (fp32 512x512) -> bf16 MFMA B-frag order:
//     W1p[(((nt*16+kt)*64 + lane)*8 + j)] = bf16(W1[kt*32+(lane>>4)*8+j][nt*16+(lane&15)])
__global__ __launch_bounds__(256) void pack_w1_kernel(
    const float* __restrict__ W1, unsigned short* __restrict__ W1p) {
  int t = blockIdx.x * 256 + threadIdx.x;
  int k = t >> 9, n = t & 511;
  int kt = k >> 5, kr = k & 31;
  int quad = kr >> 3, j = kr & 7;
  int l = (quad << 4) | (n & 15);
  int nt = n >> 4;
  int dst = ((((nt << 4) + kt) * 64 + l) << 3) + j;
  W1p[dst] = f2bf(W1[t]);
}

// --- K2: c[b][u] = sum_d H[b][d]*W2[d][u] + b1[u] + b2[u]
__global__ __launch_bounds__(512) void compute_c_kernel(
    const float* __restrict__ H, const float* __restrict__ W2,
    const float* __restrict__ b1, const float* __restrict__ b2,
    float* __restrict__ cvec) {
  const int b = blockIdx.x, u = threadIdx.x;
  __shared__ float hs[512];
  hs[u] = H[(b << 9) + u];
  __syncthreads();
  float s = 0.f;
#pragma unroll 8
  for (int d = 0; d < 512; d++) s = fmaf(hs[d], W2[(d << 9) + u], s);
  cvec[(b << 9) + u] = s + b1[u] + b2[u];
}

// --- K3: scores + softmax partials + context partials.
// grid 2048 (= 64 b * 32 strips of 64 rows), 256 thr (4 waves x 16 rows).
__global__ __launch_bounds__(256, 2) void scores_ctx_kernel(
    const float* __restrict__ EO, const unsigned short* __restrict__ W1p,
    const float* __restrict__ cvec, const float* __restrict__ V,
    float* __restrict__ scores, float* __restrict__ m_ws,
    float* __restrict__ l_ws, float* __restrict__ ck_ws) {
  __shared__ __align__(16) unsigned short Bs[3][8192];  // 3 x 16KB nt tiles
  __shared__ float cs[512], vs[512];
  __shared__ float sc_l[64], p_l[64];
  __shared__ __align__(16) float cpart[4][512];

  const int tid = threadIdx.x;
  const int b = blockIdx.x >> 5;
  const int strip = blockIdx.x & 31;
  const int s0 = strip << 6;   // *64
  const int lane = tid & 63, wave = tid >> 6;
  const int quad = lane >> 4, col = lane & 15;

  const uint4* W1p4 = (const uint4*)W1p;  // one 16KB tile = 1024 uint4

  // ---- kick off DMA of tile 0 (4 loads/wave); retired by __syncthreads
#pragma unroll
  for (int i = 0; i < 4; i++)
    ASYNC_CP16(W1p4 + i * 256 + wave * 64 + lane,
               ((char*)&Bs[0][0]) + (i * 256 + wave * 64) * 16);

  cs[tid] = cvec[(b << 9) + tid];
  cs[tid + 256] = cvec[(b << 9) + 256 + tid];
  vs[tid] = V[tid];
  vs[tid + 256] = V[256 + tid];

  // ---- A-fragments straight from global: 16 rows x K=512, fp32 -> bf16.
  //      Lane (quad,col) holds row col, k = kt*32 + quad*8 + j.  64 VGPRs.
  bf16x8 afrag[16];
  {
    const float* rp =
        EO + ((size_t)(b * NS + s0 + wave * 16 + col)) * NE + quad * 8;
#pragma unroll
    for (int kt = 0; kt < 16; kt++) {
      float4 x = *(const float4*)(rp + kt * 32);
      float4 y = *(const float4*)(rp + kt * 32 + 4);
      union { short s[8]; bf16x8 v; } u0;
      u0.s[0] = (short)f2bf(x.x); u0.s[1] = (short)f2bf(x.y);
      u0.s[2] = (short)f2bf(x.z); u0.s[3] = (short)f2bf(x.w);
      u0.s[4] = (short)f2bf(y.x); u0.s[5] = (short)f2bf(y.y);
      u0.s[6] = (short)f2bf(y.z); u0.s[7] = (short)f2bf(y.w);
      afrag[kt] = u0.v;
    }
  }

  __syncthreads();  // full drain: tile 0 + cs/vs/afrag loads all complete

  // ---- prefetch tiles 1 and 2 (8 loads/wave outstanding from here on)
#pragma unroll
  for (int tph = 1; tph <= 2; tph++)
#pragma unroll
    for (int i = 0; i < 4; i++)
      ASYNC_CP16(W1p4 + tph * 1024 + i * 256 + wave * 64 + lane,
                 ((char*)&Bs[tph][0]) + (i * 256 + wave * 64) * 16);

  float sacc[4] = {0.f, 0.f, 0.f, 0.f};
  int cur = 0;  // t % 3

  for (int t = 0; t < 32; t++) {
    // wait for MY 4 loads of tile t only; tiles t+1,t+2 stay in flight.
    // All waves do this before the barrier => tile t globally ready.
    if (t < 30)       WAITVM(8);
    else if (t == 30) WAITVM(4);
    else              WAITVM(0);
    __builtin_amdgcn_s_barrier();
    __builtin_amdgcn_sched_barrier(0);  // keep ds_reads below the wait+bar

    f32x4 acc = {0.f, 0.f, 0.f, 0.f};
    const bf16x8* bp = (const bf16x8*)&Bs[cur][0];
#pragma unroll
    for (int kt = 0; kt < 16; kt++) {
      bf16x8 bfr = bp[kt * 64 + lane];
      acc = __builtin_amdgcn_mfma_f32_16x16x32_bf16(afrag[kt], bfr, acc, 0, 0, 0);
    }
    // fused epilogue: score partial += tanh(acc + c[u]) * V[u]
    int u = (t << 4) + col;
    float cu = cs[u], vu = vs[u];
#pragma unroll
    for (int r = 0; r < 4; r++)
      sacc[r] += tanh_fast(acc[r] + cu) * vu;

    __builtin_amdgcn_sched_barrier(0);  // reads of Bs[cur] stay above
    __builtin_amdgcn_s_barrier();       // all waves done reading Bs[cur]
    if (t + 3 < 32) {                   // refill the just-freed buffer
#pragma unroll
      for (int i = 0; i < 4; i++)
        ASYNC_CP16(W1p4 + (t + 3) * 1024 + i * 256 + wave * 64 + lane,
                   ((char*)&Bs[cur][0]) + (i * 256 + wave * 64) * 16);
    }
    cur = (cur == 2) ? 0 : cur + 1;
  }

  // ---- reduce scores over the 16 col-lanes of each quad-group
#pragma unroll
  for (int m = 1; m < 16; m <<= 1)
#pragma unroll
    for (int r = 0; r < 4; r++)
      sacc[r] += __shfl_xor(sacc[r], m, 64);

  if (col == 0) {
#pragma unroll
    for (int r = 0; r < 4; r++) {
      int row = wave * 16 + quad * 4 + r;   // C/D: row = quad*4 + reg
      sc_l[row] = sacc[r];
      scores[(size_t)b * NS + s0 + row] = sacc[r];  // raw scores
    }
  }
  __syncthreads();

  // ---- strip max + l over the 64 rows (wave 0)
  if (wave == 0) {
    float m0 = sc_l[lane];
#pragma unroll
    for (int off = 32; off; off >>= 1) m0 = fmaxf(m0, __shfl_xor(m0, off, 64));
    float p = __expf(sc_l[lane] - m0);
    p_l[lane] = p;
#pragma unroll
    for (int off = 32; off; off >>= 1) p += __shfl_xor(p, off, 64);
    if (lane == 0) {
      m_ws[b * 32 + strip] = m0;
      l_ws[b * 32 + strip] = p;
    }
  }
  __syncthreads();

  // ---- context partials from register-resident bf16 EO fragments.
  // lane holds row (wave*16 + col), e = kt*32 + quad*8 + j.
  const float p0 = p_l[wave * 16 + col];
#pragma unroll
  for (int kt = 0; kt < 16; kt++) {
    float v[8];
#pragma unroll
    for (int j = 0; j < 8; j++) v[j] = p0 * bf2f(afrag[kt][j]);
#pragma unroll
    for (int m = 1; m < 16; m <<= 1)
#pragma unroll
      for (int j = 0; j < 8; j++) v[j] += __shfl_xor(v[j], m, 64);
    if (col == 0) {
      float* dst = &cpart[wave][kt * 32 + quad * 8];
      *(float4*)dst = make_float4(v[0], v[1], v[2], v[3]);
      *(float4*)(dst + 4) = make_float4(v[4], v[5], v[6], v[7]);
    }
  }
  __syncthreads();

  // ---- fold 4 wave-partials, write strip context partial to ws
  {
    float2 s = {0.f, 0.f};
#pragma unroll
    for (int w = 0; w < 4; w++) {
      float2 t = *(const float2*)&cpart[w][tid * 2];
      s.x += t.x; s.y += t.y;
    }
    *(float2*)&ck_ws[((size_t)(b * 32 + strip)) * 512 + tid * 2] = s;
  }
}

// --- K4: combine 32 strips: context + normalized weights.  64 blocks x 256.
__global__ __launch_bounds__(256) void combine_kernel(
    const float* __restrict__ m_ws, const float* __restrict__ l_ws,
    const float* __restrict__ ck_ws, float* __restrict__ ctx,
    float* __restrict__ w /* raw scores in, weights out */) {
  const int b = blockIdx.x, tid = threadIdx.x;
  __shared__ float msh[32], lsh[32];
  if (tid < 32) {
    msh[tid] = m_ws[b * 32 + tid];
    lsh[tid] = l_ws[b * 32 + tid];
  }
  __syncthreads();
  float M = msh[0];
#pragma unroll
  for (int k = 1; k < 32; k++) M = fmaxf(M, msh[k]);
  float L = 0.f;
#pragma unroll
  for (int k = 0; k < 32; k++) L += lsh[k] * __expf(msh[k] - M);
  const float invL = 1.f / L;

  float2 acc = {0.f, 0.f};
#pragma unroll
  for (int k = 0; k < 32; k++) {
    float sc = __expf(msh[k] - M);
    float2 t = *(const float2*)&ck_ws[((size_t)(b * 32 + k)) * 512 + tid * 2];
    acc.x += sc * t.x; acc.y += sc * t.y;
  }
  acc.x *= invL; acc.y *= invL;
  *(float2*)&ctx[(b << 9) + tid * 2] = acc;

  float* row = w + (size_t)b * NS;
#pragma unroll
  for (int i = 0; i < 8; i++) {
    float s = row[i * 256 + tid];
    row[i * 256 + tid] = __expf(s - M) * invL;
  }
}

extern "C" void kernel_launch(void* const* d_in, const int* in_sizes, int n_in,
                              void* d_out, int out_size, void* d_ws, size_t ws_size,
                              hipStream_t stream) {
  (void)in_sizes; (void)n_in; (void)out_size; (void)ws_size;
  const float* H  = (const float*)d_in[0];
  const float* EO = (const float*)d_in[1];
  const float* W1 = (const float*)d_in[2];
  const float* b1 = (const float*)d_in[3];
  const float* W2 = (const float*)d_in[4];
  const float* b2 = (const float*)d_in[5];
  const float* V  = (const float*)d_in[6];
  // d_in[7] = bv: softmax is shift-invariant -> unused.

  float* out_ctx = (float*)d_out;            // [64*512]
  float* out_w   = (float*)d_out + NB * NE;  // [64*2048] raw scores -> weights

  char* ws = (char*)d_ws;
  unsigned short* W1p = (unsigned short*)ws;            // 512 KB
  float* cvec = (float*)(ws + 512 * 1024);              // 128 KB
  float* m_ws = (float*)(ws + 640 * 1024);              // 8 KB
  float* l_ws = (float*)(ws + 656 * 1024);              // 8 KB
  float* ck_ws = (float*)(ws + 672 * 1024);             // 4 MB

  pack_w1_kernel<<<1024, 256, 0, stream>>>(W1, W1p);
  compute_c_kernel<<<NB, 512, 0, stream>>>(H, W2, b1, b2, cvec);
  scores_ctx_kernel<<<2048, 256, 0, stream>>>(EO, W1p, cvec, V, out_w,
                                              m_ws, l_ws, ck_ws);
  combine_kernel<<<NB, 256, 0, stream>>>(m_ws, l_ws, ck_ws, out_ctx, out_w);
}